// Round 2
// baseline (532.445 us; speedup 1.0000x reference)
//
#include <hip/hip_runtime.h>

#define HH 24
#define MM 48
#define CC 8
#define PP 8
#define IJ (HH * MM)              // 1152
#define NBLK (IJ * IJ)            // 1327104 (i,j,l,k) blocks of 64 floats

// ---------------------------------------------------------------------------
// Main kernel: u[c] += sum_{i,j,l,k,p} A[i,j]*B[l,k]*M[i,j,l,k,c,p]*y_rev[j+k,p]
// 16 threads cooperate on one 64-float (c,p) block; thread's float4 slot is
// fixed: pos = tid&15, c = pos>>1, p-half = pos&1. Wave of 64 lanes covers 4
// consecutive blocks = 1KB contiguous -> fully coalesced dwordx4 loads.
// ---------------------------------------------------------------------------
__global__ __launch_bounds__(256) void
dsc_big(const float* __restrict__ M,
        const float* __restrict__ y_rev,
        const float* __restrict__ sigma,
        const float* __restrict__ lambda_e,
        const float* __restrict__ phi,
        const float* __restrict__ phi_tilde,
        float* __restrict__ out)
{
    __shared__ float A[IJ];
    __shared__ float B[IJ];
    __shared__ float4 y4[2 * MM * 2];   // 96 rows x 2 float4 (P=8)
    __shared__ float red[256];

    const int tid = threadIdx.x;

    for (int t = tid; t < IJ; t += 256) {
        int i = t / MM;            // 0..23
        int j = t - i * MM;        // 0..47
        // phi is (Mdim,H) row-major: phi[j,i] at j*HH+i
        A[t] = sqrtf(sqrtf(lambda_e[i])) * phi[j * HH + i];
        B[t] = sqrtf(sqrtf(sigma[i]))    * phi_tilde[j * HH + i];
    }
    const float4* yg = (const float4*)y_rev;
    for (int t = tid; t < 2 * MM * 2; t += 256) y4[t] = yg[t];
    __syncthreads();

    const int pos = tid & 15;
    const int ph  = pos & 1;
    const unsigned group   = (blockIdx.x * 256u + tid) >> 4;
    const unsigned nGroups = gridDim.x * 16u;

    const float4* M4 = (const float4*)M;
    float acc = 0.0f;
    for (unsigned b = group; b < NBLK; b += nGroups) {
        unsigned ij = b / IJ;              // = i*48+j  -> direct A index
        unsigned lk = b - ij * IJ;         // = l*48+k  -> direct B index
        unsigned j  = ij % MM;
        unsigned k  = lk % MM;
        float w = A[ij] * B[lk];
        float4 mv = M4[(size_t)b * 16u + pos];
        float4 yv = y4[(j + k) * 2u + ph];
        acc += w * (mv.x * yv.x + mv.y * yv.y + mv.z * yv.z + mv.w * yv.w);
    }

    red[tid] = acc;
    __syncthreads();
    if (tid < CC) {
        float s = 0.0f;
        #pragma unroll
        for (int g = 0; g < 16; ++g)
            s += red[g * 16 + tid * 2] + red[g * 16 + tid * 2 + 1];
        atomicAdd(out + tid, s);
    }
}

// ---------------------------------------------------------------------------
// Small terms (one block):
//   term1: M_tilde[0,0] @ y_rev[0]
//   term2: sum_{i,j,p} A[i,j] * M_tilde[i,j,c,p] * y_rev[j,p]
//   term3: sum_{l,k,p} B[l,k] * M[l,k,0,0,c,p]   * y_rev[k,p]
// ---------------------------------------------------------------------------
__global__ __launch_bounds__(256) void
dsc_small(const float* __restrict__ M,
          const float* __restrict__ M_tilde,
          const float* __restrict__ y_rev,
          const float* __restrict__ sigma,
          const float* __restrict__ lambda_e,
          const float* __restrict__ phi,
          const float* __restrict__ phi_tilde,
          float* __restrict__ out)
{
    __shared__ float A[IJ];
    __shared__ float B[IJ];
    __shared__ float4 y4[MM * 2];   // first 48 rows only (y_m)
    __shared__ float red[256];

    const int tid = threadIdx.x;
    for (int t = tid; t < IJ; t += 256) {
        int i = t / MM;
        int j = t - i * MM;
        A[t] = sqrtf(sqrtf(lambda_e[i])) * phi[j * HH + i];
        B[t] = sqrtf(sqrtf(sigma[i]))    * phi_tilde[j * HH + i];
    }
    const float4* yg = (const float4*)y_rev;
    for (int t = tid; t < MM * 2; t += 256) y4[t] = yg[t];
    __syncthreads();

    const int group = tid >> 4;    // 0..15
    const int pos   = tid & 15;
    const int ph    = pos & 1;

    const float4* Mt4 = (const float4*)M_tilde;
    const float4* M4  = (const float4*)M;

    float acc = 0.0f;
    // term2: 1152 blocks of 64 floats in M_tilde
    for (int b = group; b < IJ; b += 16) {
        int j = b % MM;
        float4 mv = Mt4[b * 16 + pos];
        float4 yv = y4[j * 2 + ph];
        acc += A[b] * (mv.x * yv.x + mv.y * yv.y + mv.z * yv.z + mv.w * yv.w);
    }
    // term3: M[l,k,0,0,c,p] -> block stride 24*48*64 floats = 18432 float4
    for (int b = group; b < IJ; b += 16) {
        int k = b % MM;
        float4 mv = M4[(size_t)b * 18432u + pos];
        float4 yv = y4[k * 2 + ph];
        acc += B[b] * (mv.x * yv.x + mv.y * yv.y + mv.z * yv.z + mv.w * yv.w);
    }
    // term1: M_tilde[0,0] block only, y row 0
    if (group == 0) {
        float4 mv = Mt4[pos];
        float4 yv = y4[ph];
        acc += (mv.x * yv.x + mv.y * yv.y + mv.z * yv.z + mv.w * yv.w);
    }

    red[tid] = acc;
    __syncthreads();
    if (tid < CC) {
        float s = 0.0f;
        #pragma unroll
        for (int g = 0; g < 16; ++g)
            s += red[g * 16 + tid * 2] + red[g * 16 + tid * 2 + 1];
        atomicAdd(out + tid, s);
    }
}

extern "C" void kernel_launch(void* const* d_in, const int* in_sizes, int n_in,
                              void* d_out, int out_size, void* d_ws, size_t ws_size,
                              hipStream_t stream)
{
    const float* y_rev     = (const float*)d_in[0];
    const float* M_tilde   = (const float*)d_in[1];
    const float* M         = (const float*)d_in[2];
    const float* sigma     = (const float*)d_in[3];
    const float* lambda_e  = (const float*)d_in[4];
    const float* phi       = (const float*)d_in[5];
    const float* phi_tilde = (const float*)d_in[6];
    float* out = (float*)d_out;

    // d_out is re-poisoned to 0xAA before every launch; zero it on-stream.
    hipMemsetAsync(out, 0, out_size * sizeof(float), stream);

    dsc_small<<<1, 256, 0, stream>>>(M, M_tilde, y_rev, sigma, lambda_e,
                                     phi, phi_tilde, out);
    dsc_big<<<2048, 256, 0, stream>>>(M, y_rev, sigma, lambda_e,
                                      phi, phi_tilde, out);
}

// Round 4
// 462.620 us; speedup vs baseline: 1.1509x; 1.1509x over previous
//
#include <hip/hip_runtime.h>

#define HH 24
#define MM 48
#define CC 8
#define PP 8
#define IJ (HH * MM)              // 1152
#define NBLK (IJ * IJ)            // 1327104 (i,j,l,k) blocks of 64 floats
#define GRID_BIG 2048
#define TPB 256
#define GROUPS_PER_BLOCK (TPB / 8)                 // 32 groups of 8 lanes
#define NGROUPS (GRID_BIG * GROUPS_PER_BLOCK)      // 65536

__device__ __forceinline__ float dot4(const float4 a, const float4 b) {
    return a.x * b.x + a.y * b.y + a.z * b.z + a.w * b.w;
}

// ---------------------------------------------------------------------------
// Kernel 1: big term + distributed small terms -> per-block partials in d_ws.
// 8 lanes cooperate on one 64-float (c,p) block of M; lane q owns channel c=q
// and loads 32 consecutive bytes (2x float4). A wave covers 8 consecutive
// blocks = 2 KB contiguous -> fully coalesced dwordx4 loads.
//   u[c] += sum A[ij]*B[lk]*M[ij,lk,c,p]*y_rev[j+k,p]        (all blocks)
//   u[c] += A[b]*M_tilde[b,c,p]*y_m[b%48,p]                  (blocks b<1152)
//   u[c] += B[b]*M[b*1152 blocks,c,p]*y_m[b%48,p]            (blocks b<1152)
//   u[c] += M_tilde[0,0,c,p]*y_rev[0,p]                      (block 0)
// ---------------------------------------------------------------------------
__global__ __launch_bounds__(TPB) void
dsc_main(const float* __restrict__ M,
         const float* __restrict__ M_tilde,
         const float* __restrict__ y_rev,
         const float* __restrict__ sigma,
         const float* __restrict__ lambda_e,
         const float* __restrict__ phi,
         const float* __restrict__ phi_tilde,
         float* __restrict__ ws)
{
    __shared__ float A[IJ];
    __shared__ float B[IJ];
    __shared__ float4 y4[2 * MM * 2];   // 96 rows x 2 float4 (P=8)
    __shared__ float red[TPB];

    const int tid = threadIdx.x;
    const int bid = blockIdx.x;

    for (int t = tid; t < IJ; t += TPB) {
        int i = t / MM;            // 0..23
        int j = t - i * MM;        // 0..47
        // phi is (Mdim,H) row-major: phi[j,i] at j*HH+i
        A[t] = sqrtf(sqrtf(lambda_e[i])) * phi[j * HH + i];
        B[t] = sqrtf(sqrtf(sigma[i]))    * phi_tilde[j * HH + i];
    }
    const float4* yg = (const float4*)y_rev;
    for (int t = tid; t < 2 * MM * 2; t += TPB) y4[t] = yg[t];
    __syncthreads();

    const int q = tid & 7;                       // lane's channel c
    const unsigned group   = ((unsigned)bid * TPB + tid) >> 3;

    const float4* M4  = (const float4*)M;
    const float4* Mt4 = (const float4*)M_tilde;

    float acc = 0.0f;
    for (unsigned b = group; b < NBLK; b += NGROUPS) {
        unsigned ij = b / IJ;              // = i*48+j  -> direct A index
        unsigned lk = b - ij * IJ;         // = l*48+k  -> direct B index
        unsigned j  = ij % MM;
        unsigned k  = lk % MM;
        float w = A[ij] * B[lk];
        size_t base = (size_t)b * 16u + (unsigned)(q * 2);
        float4 m0 = M4[base];
        float4 m1 = M4[base + 1];
        unsigned yr = (j + k) * 2u;
        acc += w * (dot4(m0, y4[yr]) + dot4(m1, y4[yr + 1]));
    }

    // distributed small terms
    if (bid < IJ) {
        const int g = tid >> 3;            // group within block
        if (g == 0) {
            // term2: M_tilde block bid, weight A[bid], y row bid%48
            unsigned j = (unsigned)bid % MM;
            size_t base = (size_t)bid * 16u + (unsigned)(q * 2);
            float4 m0 = Mt4[base];
            float4 m1 = Mt4[base + 1];
            acc += A[bid] * (dot4(m0, y4[j * 2]) + dot4(m1, y4[j * 2 + 1]));
        } else if (g == 1) {
            // term3: M[l,k,0,0] block = flat block bid*1152, weight B[bid]
            unsigned k = (unsigned)bid % MM;
            size_t base = (size_t)bid * 1152u * 16u + (unsigned)(q * 2);
            float4 m0 = M4[base];
            float4 m1 = M4[base + 1];
            acc += B[bid] * (dot4(m0, y4[k * 2]) + dot4(m1, y4[k * 2 + 1]));
        } else if (g == 2 && bid == 0) {
            // term1: M_tilde[0,0] @ y_rev[0]
            size_t base = (unsigned)(q * 2);
            float4 m0 = Mt4[base];
            float4 m1 = Mt4[base + 1];
            acc += dot4(m0, y4[0]) + dot4(m1, y4[1]);
        }
    }

    red[tid] = acc;
    __syncthreads();
    if (tid < CC) {
        float s = 0.0f;
        #pragma unroll
        for (int g = 0; g < GROUPS_PER_BLOCK; ++g)
            s += red[g * 8 + tid];
        ws[(size_t)bid * CC + tid] = s;
    }
}

// ---------------------------------------------------------------------------
// Kernel 2: reduce 2048x8 partials from d_ws -> d_out (8 floats). One block.
// Even float4s hold c=0..3, odd float4s hold c=4..7.
// ---------------------------------------------------------------------------
__global__ __launch_bounds__(TPB) void
dsc_reduce(const float* __restrict__ ws, float* __restrict__ out)
{
    __shared__ float4 redE[TPB];
    __shared__ float4 redO[TPB];

    const int tid = threadIdx.x;
    const float4* w4 = (const float4*)ws;   // 2048*8/4 = 4096 float4

    float4 accE = make_float4(0.f, 0.f, 0.f, 0.f);
    float4 accO = make_float4(0.f, 0.f, 0.f, 0.f);
    #pragma unroll
    for (int u = 0; u < 16; u += 2) {
        float4 e = w4[tid * 16 + u];
        float4 o = w4[tid * 16 + u + 1];
        accE.x += e.x; accE.y += e.y; accE.z += e.z; accE.w += e.w;
        accO.x += o.x; accO.y += o.y; accO.z += o.z; accO.w += o.w;
    }
    redE[tid] = accE;
    redO[tid] = accO;
    __syncthreads();
    for (int s = TPB / 2; s > 0; s >>= 1) {
        if (tid < s) {
            float4 a = redE[tid], b = redE[tid + s];
            redE[tid] = make_float4(a.x + b.x, a.y + b.y, a.z + b.z, a.w + b.w);
            a = redO[tid]; b = redO[tid + s];
            redO[tid] = make_float4(a.x + b.x, a.y + b.y, a.z + b.z, a.w + b.w);
        }
        __syncthreads();
    }
    if (tid == 0) {
        float4 e = redE[0], o = redO[0];
        out[0] = e.x; out[1] = e.y; out[2] = e.z; out[3] = e.w;
        out[4] = o.x; out[5] = o.y; out[6] = o.z; out[7] = o.w;
    }
}

extern "C" void kernel_launch(void* const* d_in, const int* in_sizes, int n_in,
                              void* d_out, int out_size, void* d_ws, size_t ws_size,
                              hipStream_t stream)
{
    const float* y_rev     = (const float*)d_in[0];
    const float* M_tilde   = (const float*)d_in[1];
    const float* M         = (const float*)d_in[2];
    const float* sigma     = (const float*)d_in[3];
    const float* lambda_e  = (const float*)d_in[4];
    const float* phi       = (const float*)d_in[5];
    const float* phi_tilde = (const float*)d_in[6];
    float* out = (float*)d_out;
    float* ws  = (float*)d_ws;

    dsc_main<<<GRID_BIG, TPB, 0, stream>>>(M, M_tilde, y_rev, sigma, lambda_e,
                                           phi, phi_tilde, ws);
    dsc_reduce<<<1, TPB, 0, stream>>>(ws, out);
}

// Round 5
// 461.486 us; speedup vs baseline: 1.1538x; 1.0025x over previous
//
#include <hip/hip_runtime.h>

#define HH 24
#define MM 48
#define CC 8
#define IJ (HH * MM)              // 1152
#define NBLK (IJ * IJ)            // 1327104 (i,j,l,k) blocks of 64 floats
#define GRID_BIG 2048
#define TPB 256
#define LPG 4                     // lanes per 256B block -> 64B per lane
#define GPB (TPB / LPG)           // 64 groups per workgroup
#define NG (GRID_BIG * GPB)       // 131072 groups

__device__ __forceinline__ float dot4(const float4 a, const float4 b) {
    return a.x * b.x + a.y * b.y + a.z * b.z + a.w * b.w;
}

// ---------------------------------------------------------------------------
// Kernel 1: big term + distributed small terms -> per-block partials in d_ws.
// 4 lanes cooperate on one 64-float (c,p) block of M; lane q loads 64B
// (4x float4) = channels 2q and 2q+1. A wave covers 16 consecutive blocks
// = 4KB contiguous -> fully coalesced dwordx4 loads, ~10 iters per lane.
// ---------------------------------------------------------------------------
__global__ __launch_bounds__(TPB) void
dsc_main(const float* __restrict__ M,
         const float* __restrict__ M_tilde,
         const float* __restrict__ y_rev,
         const float* __restrict__ sigma,
         const float* __restrict__ lambda_e,
         const float* __restrict__ phi,
         const float* __restrict__ phi_tilde,
         float* __restrict__ ws)
{
    __shared__ float A[IJ];
    __shared__ float B[IJ];
    __shared__ float4 y4[2 * MM * 2];   // 96 rows x 2 float4 (P=8)
    __shared__ float red0[TPB];
    __shared__ float red1[TPB];

    const int tid = threadIdx.x;
    const int bid = blockIdx.x;

    for (int t = tid; t < IJ; t += TPB) {
        int i = t / MM;            // 0..23
        int j = t - i * MM;        // 0..47
        // phi is (Mdim,H) row-major: phi[j,i] at j*HH+i
        A[t] = sqrtf(sqrtf(lambda_e[i])) * phi[j * HH + i];
        B[t] = sqrtf(sqrtf(sigma[i]))    * phi_tilde[j * HH + i];
    }
    const float4* yg = (const float4*)y_rev;
    for (int t = tid; t < 2 * MM * 2; t += TPB) y4[t] = yg[t];
    __syncthreads();

    const int q = tid & (LPG - 1);                     // lane slot in group
    const unsigned group = ((unsigned)bid * TPB + tid) >> 2;

    const float4* M4  = (const float4*)M;
    const float4* Mt4 = (const float4*)M_tilde;

    float acc0 = 0.0f;   // channel 2q
    float acc1 = 0.0f;   // channel 2q+1
    #pragma unroll 2
    for (unsigned b = group; b < NBLK; b += NG) {
        unsigned ij = b / IJ;              // = i*48+j  -> direct A index
        unsigned lk = b - ij * IJ;         // = l*48+k  -> direct B index
        unsigned j  = ij % MM;
        unsigned k  = lk % MM;
        float w = A[ij] * B[lk];
        size_t base = (size_t)b * 16u + (unsigned)(q * 4);
        float4 m0 = M4[base + 0];
        float4 m1 = M4[base + 1];
        float4 m2 = M4[base + 2];
        float4 m3 = M4[base + 3];
        unsigned yr = (j + k) * 2u;
        float4 ya = y4[yr], yb = y4[yr + 1];
        acc0 += w * (dot4(m0, ya) + dot4(m1, yb));
        acc1 += w * (dot4(m2, ya) + dot4(m3, yb));
    }

    // distributed small terms (blocks bid < 1152)
    if (bid < IJ) {
        const int g = tid >> 2;            // group index within block
        if (g == 0) {
            // term2: M_tilde block bid, weight A[bid], y row bid%48
            unsigned j = (unsigned)bid % MM;
            size_t base = (size_t)bid * 16u + (unsigned)(q * 4);
            float4 m0 = Mt4[base + 0], m1 = Mt4[base + 1];
            float4 m2 = Mt4[base + 2], m3 = Mt4[base + 3];
            float4 ya = y4[j * 2], yb = y4[j * 2 + 1];
            acc0 += A[bid] * (dot4(m0, ya) + dot4(m1, yb));
            acc1 += A[bid] * (dot4(m2, ya) + dot4(m3, yb));
        } else if (g == 1) {
            // term3: M[l,k,0,0] block = flat block bid*1152, weight B[bid]
            unsigned k = (unsigned)bid % MM;
            size_t base = (size_t)bid * 1152u * 16u + (unsigned)(q * 4);
            float4 m0 = M4[base + 0], m1 = M4[base + 1];
            float4 m2 = M4[base + 2], m3 = M4[base + 3];
            float4 ya = y4[k * 2], yb = y4[k * 2 + 1];
            acc0 += B[bid] * (dot4(m0, ya) + dot4(m1, yb));
            acc1 += B[bid] * (dot4(m2, ya) + dot4(m3, yb));
        } else if (g == 2 && bid == 0) {
            // term1: M_tilde[0,0] @ y_rev[0]
            size_t base = (unsigned)(q * 4);
            float4 m0 = Mt4[base + 0], m1 = Mt4[base + 1];
            float4 m2 = Mt4[base + 2], m3 = Mt4[base + 3];
            float4 ya = y4[0], yb = y4[1];
            acc0 += dot4(m0, ya) + dot4(m1, yb);
            acc1 += dot4(m2, ya) + dot4(m3, yb);
        }
    }

    red0[tid] = acc0;
    red1[tid] = acc1;
    __syncthreads();
    if (tid < CC) {
        const int qq  = tid >> 1;          // lane slot owning this channel pair
        const int par = tid & 1;           // 0 -> acc0, 1 -> acc1
        const float* r = par ? red1 : red0;
        float s = 0.0f;
        #pragma unroll
        for (int g = 0; g < GPB; ++g)
            s += r[g * LPG + qq];
        ws[(size_t)bid * CC + tid] = s;
    }
}

// ---------------------------------------------------------------------------
// Kernel 2: reduce 2048x8 partials from d_ws -> d_out (8 floats). One block.
// Even float4s hold c=0..3, odd float4s hold c=4..7.
// ---------------------------------------------------------------------------
__global__ __launch_bounds__(TPB) void
dsc_reduce(const float* __restrict__ ws, float* __restrict__ out)
{
    __shared__ float4 redE[TPB];
    __shared__ float4 redO[TPB];

    const int tid = threadIdx.x;
    const float4* w4 = (const float4*)ws;   // 2048*8/4 = 4096 float4

    float4 accE = make_float4(0.f, 0.f, 0.f, 0.f);
    float4 accO = make_float4(0.f, 0.f, 0.f, 0.f);
    #pragma unroll
    for (int u = 0; u < 16; u += 2) {
        float4 e = w4[tid * 16 + u];
        float4 o = w4[tid * 16 + u + 1];
        accE.x += e.x; accE.y += e.y; accE.z += e.z; accE.w += e.w;
        accO.x += o.x; accO.y += o.y; accO.z += o.z; accO.w += o.w;
    }
    redE[tid] = accE;
    redO[tid] = accO;
    __syncthreads();
    for (int s = TPB / 2; s > 0; s >>= 1) {
        if (tid < s) {
            float4 a = redE[tid], b = redE[tid + s];
            redE[tid] = make_float4(a.x + b.x, a.y + b.y, a.z + b.z, a.w + b.w);
            a = redO[tid]; b = redO[tid + s];
            redO[tid] = make_float4(a.x + b.x, a.y + b.y, a.z + b.z, a.w + b.w);
        }
        __syncthreads();
    }
    if (tid == 0) {
        float4 e = redE[0], o = redO[0];
        out[0] = e.x; out[1] = e.y; out[2] = e.z; out[3] = e.w;
        out[4] = o.x; out[5] = o.y; out[6] = o.z; out[7] = o.w;
    }
}

extern "C" void kernel_launch(void* const* d_in, const int* in_sizes, int n_in,
                              void* d_out, int out_size, void* d_ws, size_t ws_size,
                              hipStream_t stream)
{
    const float* y_rev     = (const float*)d_in[0];
    const float* M_tilde   = (const float*)d_in[1];
    const float* M         = (const float*)d_in[2];
    const float* sigma     = (const float*)d_in[3];
    const float* lambda_e  = (const float*)d_in[4];
    const float* phi       = (const float*)d_in[5];
    const float* phi_tilde = (const float*)d_in[6];
    float* out = (float*)d_out;
    float* ws  = (float*)d_ws;

    dsc_main<<<GRID_BIG, TPB, 0, stream>>>(M, M_tilde, y_rev, sigma, lambda_e,
                                           phi, phi_tilde, ws);
    dsc_reduce<<<1, TPB, 0, stream>>>(ws, out);
}